// Round 13
// baseline (2724.946 us; speedup 1.0000x reference)
//
#include <hip/hip_runtime.h>
#include <hip/hip_fp16.h>

#define NN 100000
#define NE 3200000
#define NB8 12500   // NN/8, bucket width for scatter passes

// ---------------- CSR build ----------------
__global__ __launch_bounds__(256) void k_deg(const int* __restrict__ col, int* __restrict__ deg) {
    int e = blockIdx.x * 256 + threadIdx.x;
    if (e < NE) atomicAdd(&deg[col[e]], 1);
}

__global__ __launch_bounds__(256) void k_bsum(const int* __restrict__ deg, int* __restrict__ bsum) {
    __shared__ int s[256];
    int t = threadIdx.x, i = blockIdx.x * 256 + t;
    s[t] = (i < NN) ? deg[i] : 0;
    __syncthreads();
    for (int st = 128; st > 0; st >>= 1) {
        if (t < st) s[t] += s[t + st];
        __syncthreads();
    }
    if (t == 0) bsum[blockIdx.x] = s[0];
}

__global__ __launch_bounds__(512) void k_scanb(int* __restrict__ bsum, int nb) {
    __shared__ int s[512];
    int t = threadIdx.x;
    s[t] = (t < nb) ? bsum[t] : 0;
    __syncthreads();
    for (int off = 1; off < 512; off <<= 1) {
        int v = (t >= off) ? s[t - off] : 0;
        __syncthreads();
        s[t] += v;
        __syncthreads();
    }
    if (t < nb) bsum[t] = (t == 0) ? 0 : s[t - 1];
}

__global__ __launch_bounds__(256) void k_colptr(const int* __restrict__ deg, const int* __restrict__ bsum,
                                                int* __restrict__ colptr) {
    __shared__ int s[256];
    int t = threadIdx.x, i = blockIdx.x * 256 + t;
    int v = (i < NN) ? deg[i] : 0;
    s[t] = v;
    __syncthreads();
    for (int off = 1; off < 256; off <<= 1) {
        int u = (t >= off) ? s[t - off] : 0;
        __syncthreads();
        s[t] += u;
        __syncthreads();
    }
    if (i <= NN) colptr[i] = bsum[blockIdx.x] + s[t] - v;   // exclusive scan
}

__global__ __launch_bounds__(256) void k_dis(int* __restrict__ degdis) {
    int i = blockIdx.x * 256 + threadIdx.x;
    if (i < NN) {
        int d = degdis[i];
        ((float*)degdis)[i] = 1.0f / sqrtf((float)(d + 1));  // +1 self loop
    }
}

// bucketed scatter: pass p writes only cols in [p*NB8, (p+1)*NB8)
__global__ __launch_bounds__(256) void k_scatter(const int* __restrict__ ei, const int* __restrict__ colptr,
                                                 int* __restrict__ cursor, int* __restrict__ csr_row, int p) {
    int e = blockIdx.x * 256 + threadIdx.x;
    if (e < NE) {
        int c = ei[NE + e];
        int lo = p * NB8;
        if (c >= lo && c < lo + NB8) {
            int r = ei[e];
            int pos = colptr[c] + atomicAdd(&cursor[c], 1);
            csr_row[pos] = r;
        }
    }
}

// ---------------- x0 stage: h0 = fp16(dis .* x0); out = b32 + x0@W32_0^T; ring0 = fp16(mynorm(x0))
__global__ __launch_bounds__(256) void k_x0(const float* __restrict__ x, const float* __restrict__ W1,
                                            const float* __restrict__ b1, const float* __restrict__ W32,
                                            const float* __restrict__ b32, const float* __restrict__ dis,
                                            __half* __restrict__ h0, __half* __restrict__ ring0,
                                            float* __restrict__ out, float* __restrict__ Mhat,
                                            float* __restrict__ SCar) {
    __shared__ float sW1[32 * 128];
    __shared__ float sW32[64 * 32];
    __shared__ float sb1[32], sb32[64];
    int t = threadIdx.x;
    if (blockIdx.x == 0 && t == 0) SCar[0] = 1.0f;  // scale of h0 storage
    for (int i = t; i < 4096; i += 256) sW1[i] = W1[i];
    for (int i = t; i < 2048; i += 256) sW32[i] = W32[(i >> 5) * 1024 + (i & 31)];
    if (t < 32) sb1[t] = b1[t];
    if (t < 64) sb32[t] = b32[t];
    __syncthreads();
    int node = blockIdx.x * 256 + t;
    if (node >= NN) return;

    float acc[32];
#pragma unroll
    for (int c = 0; c < 32; c++) acc[c] = sb1[c];
    const float4* xr4 = (const float4*)(x + (long)node * 128);
    for (int q = 0; q < 32; q++) {
        float4 xv = xr4[q];
#pragma unroll
        for (int c = 0; c < 32; c++) {
            acc[c] += xv.x * sW1[c * 128 + q * 4] + xv.y * sW1[c * 128 + q * 4 + 1] +
                      xv.z * sW1[c * 128 + q * 4 + 2] + xv.w * sW1[c * 128 + q * 4 + 3];
        }
    }
    // relu + mynorm
    float mn = 1e30f, mx = -1e30f;
#pragma unroll
    for (int c = 0; c < 32; c++) {
        acc[c] = fmaxf(acc[c], 0.f);
        mn = fminf(mn, acc[c]);
        mx = fmaxf(mx, acc[c]);
    }
    float inv = 2.f / (mx - mn + 1e-8f);
#pragma unroll
    for (int c = 0; c < 32; c++) acc[c] = inv * (acc[c] - mn) - 1.f;  // x0 (unscaled), range [-1,1]
    // store h0 = fp16(dis * x0)
    float sc = dis[node];
    __half2* hr = (__half2*)(h0 + (long)node * 32);
#pragma unroll
    for (int q = 0; q < 16; q++) hr[q] = __floats2half2_rn(sc * acc[2 * q], sc * acc[2 * q + 1]);
    if (t == 0 && (blockIdx.x & 15) == 0) atomicMax((int*)&Mhat[0], __float_as_int(sc));
    // m0 = mynorm(x0)
    float mn2 = 1e30f, mx2 = -1e30f;
#pragma unroll
    for (int c = 0; c < 32; c++) {
        mn2 = fminf(mn2, acc[c]);
        mx2 = fmaxf(mx2, acc[c]);
    }
    float inv2 = 2.f / (mx2 - mn2 + 1e-8f);
    __half2* rr = (__half2*)(ring0 + (long)node * 32);
#pragma unroll
    for (int q = 0; q < 16; q++)
        rr[q] = __floats2half2_rn(inv2 * (acc[2 * q] - mn2) - 1.f, inv2 * (acc[2 * q + 1] - mn2) - 1.f);
    float* orow = out + (long)node * 64;
    for (int o = 0; o < 64; o++) {
        float a = sb32[o];
#pragma unroll
        for (int j = 0; j < 32; j++) a += sW32[o * 32 + j] * acc[j];
        orow[o] = a;
    }
}

// ---------------- one SGConv layer; 8 nodes/wave, 8 lanes/node, 8B gathers ----------------
// launch_bounds (256,5): 5 blocks/CU (VGPR cap 102, LDS 13.3KB*5=67KB) -> ~67% more gathers in flight
__global__ __launch_bounds__(256, 5) void k_layer(const __half* __restrict__ hin, __half* __restrict__ hout,
                                                  __half* __restrict__ ring, const float* __restrict__ dis,
                                                  const int* __restrict__ colptr, const int* __restrict__ csr_row,
                                                  const float* __restrict__ Wck, const float* __restrict__ bck,
                                                  const float* __restrict__ W32k, float* __restrict__ out,
                                                  float* __restrict__ Mhat, float* __restrict__ SCar, int k,
                                                  int rawfeat) {
    __shared__ float sWc[32 * 33];
    __shared__ float sW[64 * 33];
    __shared__ float sbc[32];
    int t = threadIdx.x;
    float SCin = SCar[k - 1];
    float SCk = SCin * fmaxf(Mhat[k - 1], 1e-30f);
    if (t == 0) SCar[k] = SCk;  // all blocks write same value
    float invSCk = 1.0f / SCk;
    for (int i = t; i < 1024; i += 256) sWc[(i >> 5) * 33 + (i & 31)] = Wck[i];
    for (int i = t; i < 2048; i += 256) sW[(i >> 5) * 33 + (i & 31)] = W32k[(i >> 5) * 1024 + (i & 31)];
    if (t < 32) sbc[t] = bck[t];
    __syncthreads();

    int wave = t >> 6, lane = t & 63;
    int sub = lane >> 3, q = lane & 7;
    int node = blockIdx.x * 32 + wave * 8 + sub;  // 3125*32 == 100000 exactly
    int sl = sub * 8;                              // lane base of my 8-group

    const uint2* __restrict__ h2 = (const uint2*)hin;  // row stride = 8 uint2 (32 halves)
    int e0 = colptr[node], e1 = colptr[node + 1];
    float di = dis[node];

    float a0, a1, a2, a3, b0 = 0.f, b1 = 0.f, b2 = 0.f, b3 = 0.f;
    {   // self-loop row
        uint2 u = h2[(long)node * 8 + q];
        float2 lo = __half22float2(*(__half2*)&u.x);
        float2 hi = __half22float2(*(__half2*)&u.y);
        a0 = lo.x; a1 = lo.y; a2 = hi.x; a3 = hi.y;
    }
    int base = e0;
    while (base + 8 <= e1) {
        int r = csr_row[base + q];  // 8 lanes fetch 8 edges of my node
#pragma unroll
        for (int j = 0; j < 8; j += 2) {
            int r0 = __shfl(r, sl + j, 64);
            int r1 = __shfl(r, sl + j + 1, 64);
            uint2 u0 = h2[(long)r0 * 8 + q];
            uint2 u1 = h2[(long)r1 * 8 + q];
            float2 lo0 = __half22float2(*(__half2*)&u0.x), hi0 = __half22float2(*(__half2*)&u0.y);
            float2 lo1 = __half22float2(*(__half2*)&u1.x), hi1 = __half22float2(*(__half2*)&u1.y);
            a0 += lo0.x; a1 += lo0.y; a2 += hi0.x; a3 += hi0.y;
            b0 += lo1.x; b1 += lo1.y; b2 += hi1.x; b3 += hi1.y;
        }
        base += 8;
    }
    int rem = e1 - base;
    if (rem > 0) {
        int r = (q < rem) ? csr_row[base + q] : 0;
        for (int j = 0; j < rem; j++) {
            int rj = __shfl(r, sl + j, 64);
            uint2 u = h2[(long)rj * 8 + q];
            float2 lo = __half22float2(*(__half2*)&u.x), hi = __half22float2(*(__half2*)&u.y);
            a0 += lo.x; a1 += lo.y; a2 += hi.x; a3 += hi.y;
        }
    }
    float g0 = di * (a0 + b0), g1 = di * (a1 + b1), g2 = di * (a2 + b2), g3 = di * (a3 + b3);
    // g* = ghat = (A h)[node][4q..4q+3] / SCin

    // y = SCin*(ghat @ Wc^T) + bc for my 4 channels
    const float* wr0 = &sWc[(4 * q + 0) * 33];
    const float* wr1 = &sWc[(4 * q + 1) * 33];
    const float* wr2 = &sWc[(4 * q + 2) * 33];
    const float* wr3 = &sWc[(4 * q + 3) * 33];
    float y0 = 0.f, y1 = 0.f, y2 = 0.f, y3 = 0.f;
#pragma unroll
    for (int s = 0; s < 8; s++) {
        float t0 = __shfl(g0, sl + s, 64);
        float t1 = __shfl(g1, sl + s, 64);
        float t2 = __shfl(g2, sl + s, 64);
        float t3 = __shfl(g3, sl + s, 64);
        int jb = 4 * s;
        y0 += wr0[jb] * t0 + wr0[jb + 1] * t1 + wr0[jb + 2] * t2 + wr0[jb + 3] * t3;
        y1 += wr1[jb] * t0 + wr1[jb + 1] * t1 + wr1[jb + 2] * t2 + wr1[jb + 3] * t3;
        y2 += wr2[jb] * t0 + wr2[jb + 1] * t1 + wr2[jb + 2] * t2 + wr2[jb + 3] * t3;
        y3 += wr3[jb] * t0 + wr3[jb + 1] * t1 + wr3[jb + 2] * t2 + wr3[jb + 3] * t3;
    }
    y0 = SCin * y0 + sbc[4 * q + 0];
    y1 = SCin * y1 + sbc[4 * q + 1];
    y2 = SCin * y2 + sbc[4 * q + 2];
    y3 = SCin * y3 + sbc[4 * q + 3];

    // store hout = fp16(di * y / SCk)
    {
        __half2 p0 = __floats2half2_rn(di * y0 * invSCk, di * y1 * invSCk);
        __half2 p1 = __floats2half2_rn(di * y2 * invSCk, di * y3 * invSCk);
        uint2 pw;
        pw.x = *(unsigned int*)&p0;
        pw.y = *(unsigned int*)&p1;
        ((uint2*)hout)[(long)node * 8 + q] = pw;
    }

    // mynorm over 32 channels = reduce over 4 regs x 8 lanes
    float mn = fminf(fminf(y0, y1), fminf(y2, y3));
    float mx = fmaxf(fmaxf(y0, y1), fmaxf(y2, y3));
#pragma unroll
    for (int m = 1; m < 8; m <<= 1) {
        mn = fminf(mn, __shfl_xor(mn, m, 64));
        mx = fmaxf(mx, __shfl_xor(mx, m, 64));
    }
    float inv = 2.f / (mx - mn + 1e-8f);
    float mv0 = inv * (y0 - mn) - 1.f, mv1 = inv * (y1 - mn) - 1.f;
    float mv2 = inv * (y2 - mn) - 1.f, mv3 = inv * (y3 - mn) - 1.f;

    // sample stored-magnitude max for next layer's scale
    if ((blockIdx.x & 15) == 0 && q == 0) {
        float rowmax = fmaxf(fabsf(mn), fabsf(mx));
        atomicMax((int*)&Mhat[k], __float_as_int(di * rowmax * invSCk));
    }

    float f0, f1, f2, f3;
    if (rawfeat) {
        f0 = y0; f1 = y1; f2 = y2; f3 = y3;
    } else {
        uint2 rv = ((const uint2*)ring)[(long)node * 8 + q];
        float2 rlo = __half22float2(*(__half2*)&rv.x);
        float2 rhi = __half22float2(*(__half2*)&rv.y);
        f0 = mv0 - rlo.x; f1 = mv1 - rlo.y; f2 = mv2 - rhi.x; f3 = mv3 - rhi.y;
    }
    {
        __half2 p0 = __floats2half2_rn(mv0, mv1);
        __half2 p1 = __floats2half2_rn(mv2, mv3);
        uint2 pw;
        pw.x = *(unsigned int*)&p0;
        pw.y = *(unsigned int*)&p1;
        ((uint2*)ring)[(long)node * 8 + q] = pw;
    }

    // out[node][8q..8q+7] += f @ W32_k^T rows
    float o0 = 0.f, o1 = 0.f, o2 = 0.f, o3 = 0.f, o4 = 0.f, o5 = 0.f, o6 = 0.f, o7 = 0.f;
#pragma unroll
    for (int s = 0; s < 8; s++) {
        float t0 = __shfl(f0, sl + s, 64);
        float t1 = __shfl(f1, sl + s, 64);
        float t2 = __shfl(f2, sl + s, 64);
        float t3 = __shfl(f3, sl + s, 64);
        int jb = 4 * s;
        const float* w = &sW[(8 * q) * 33 + jb];
        o0 += w[0] * t0 + w[1] * t1 + w[2] * t2 + w[3] * t3; w += 33;
        o1 += w[0] * t0 + w[1] * t1 + w[2] * t2 + w[3] * t3; w += 33;
        o2 += w[0] * t0 + w[1] * t1 + w[2] * t2 + w[3] * t3; w += 33;
        o3 += w[0] * t0 + w[1] * t1 + w[2] * t2 + w[3] * t3; w += 33;
        o4 += w[0] * t0 + w[1] * t1 + w[2] * t2 + w[3] * t3; w += 33;
        o5 += w[0] * t0 + w[1] * t1 + w[2] * t2 + w[3] * t3; w += 33;
        o6 += w[0] * t0 + w[1] * t1 + w[2] * t2 + w[3] * t3; w += 33;
        o7 += w[0] * t0 + w[1] * t1 + w[2] * t2 + w[3] * t3;
    }
    float4* op = (float4*)(out + (long)node * 64 + 8 * q);
    float4 v0 = op[0], v1 = op[1];
    v0.x += o0; v0.y += o1; v0.z += o2; v0.w += o3;
    v1.x += o4; v1.y += o5; v1.z += o6; v1.w += o7;
    op[0] = v0;
    op[1] = v1;
}

extern "C" void kernel_launch(void* const* d_in, const int* in_sizes, int n_in, void* d_out, int out_size,
                              void* d_ws, size_t ws_size, hipStream_t stream) {
    const float* x = (const float*)d_in[0];
    const int* ei = (const int*)d_in[1];
    const float* W1 = (const float*)d_in[2];
    const float* b1 = (const float*)d_in[3];
    const float* Wc = (const float*)d_in[4];
    const float* bc = (const float*)d_in[5];
    const float* W32 = (const float*)d_in[6];
    const float* b32 = (const float*)d_in[7];
    float* out = (float*)d_out;

    int* deg = (int*)d_ws;             // NN ints (later reused as dis float)
    int* cursor = deg + NN;            // NN
    float* Mhat = (float*)(cursor + NN);  // 64
    float* SCar = Mhat + 64;           // 64
    int* colptr = (int*)(SCar + 64);   // 100004
    int* bsum = colptr + 100004;       // 1024
    int* csr_row = bsum + 1024;        // NE
    __half* h0 = (__half*)(csr_row + NE);   // NN*32 halves
    __half* h1 = h0 + (long)NN * 32;
    __half* ring = h1 + (long)NN * 32;      // 2 slots of NN*32 halves
    float* dis = (float*)deg;

    hipMemsetAsync(deg, 0, (2 * NN + 128) * sizeof(int), stream);  // deg + cursor + Mhat + SCar
    k_deg<<<(NE + 255) / 256, 256, 0, stream>>>(ei + NE, deg);
    int NB = (NN + 255) / 256;  // 391
    k_bsum<<<NB, 256, 0, stream>>>(deg, bsum);
    k_scanb<<<1, 512, 0, stream>>>(bsum, NB);
    k_colptr<<<NB, 256, 0, stream>>>(deg, bsum, colptr);
    k_dis<<<(NN + 255) / 256, 256, 0, stream>>>(deg);
    for (int p = 0; p < 8; p++)
        k_scatter<<<(NE + 255) / 256, 256, 0, stream>>>(ei, colptr, cursor, csr_row, p);
    k_x0<<<NB, 256, 0, stream>>>(x, W1, b1, W32, b32, dis, h0, ring, out, Mhat, SCar);

    for (int k = 1; k <= 31; k++) {
        const __half* hin = (k & 1) ? h0 : h1;
        __half* hout = (k & 1) ? h1 : h0;
        __half* ringk = ring + (long)(k & 1) * NN * 32;
        int raw = (k == 1 || k == 16) ? 1 : 0;
        k_layer<<<3125, 256, 0, stream>>>(hin, hout, ringk, dis, colptr, csr_row, Wc + (k - 1) * 1024,
                                          bc + (k - 1) * 32, W32 + 32 * k, out, Mhat, SCar, k, raw);
    }
}

// Round 14
// 2459.782 us; speedup vs baseline: 1.1078x; 1.1078x over previous
//
#include <hip/hip_runtime.h>
#include <hip/hip_fp16.h>

#define NN 100000
#define NE 3200000
#define NB8 12500   // NN/8, bucket width for scatter passes

// ---------------- CSR build ----------------
__global__ __launch_bounds__(256) void k_deg(const int* __restrict__ col, int* __restrict__ deg) {
    int e = blockIdx.x * 256 + threadIdx.x;
    if (e < NE) atomicAdd(&deg[col[e]], 1);
}

__global__ __launch_bounds__(256) void k_bsum(const int* __restrict__ deg, int* __restrict__ bsum) {
    __shared__ int s[256];
    int t = threadIdx.x, i = blockIdx.x * 256 + t;
    s[t] = (i < NN) ? deg[i] : 0;
    __syncthreads();
    for (int st = 128; st > 0; st >>= 1) {
        if (t < st) s[t] += s[t + st];
        __syncthreads();
    }
    if (t == 0) bsum[blockIdx.x] = s[0];
}

__global__ __launch_bounds__(512) void k_scanb(int* __restrict__ bsum, int nb) {
    __shared__ int s[512];
    int t = threadIdx.x;
    s[t] = (t < nb) ? bsum[t] : 0;
    __syncthreads();
    for (int off = 1; off < 512; off <<= 1) {
        int v = (t >= off) ? s[t - off] : 0;
        __syncthreads();
        s[t] += v;
        __syncthreads();
    }
    if (t < nb) bsum[t] = (t == 0) ? 0 : s[t - 1];
}

__global__ __launch_bounds__(256) void k_colptr(const int* __restrict__ deg, const int* __restrict__ bsum,
                                                int* __restrict__ colptr) {
    __shared__ int s[256];
    int t = threadIdx.x, i = blockIdx.x * 256 + t;
    int v = (i < NN) ? deg[i] : 0;
    s[t] = v;
    __syncthreads();
    for (int off = 1; off < 256; off <<= 1) {
        int u = (t >= off) ? s[t - off] : 0;
        __syncthreads();
        s[t] += u;
        __syncthreads();
    }
    if (i <= NN) colptr[i] = bsum[blockIdx.x] + s[t] - v;   // exclusive scan
}

__global__ __launch_bounds__(256) void k_dis(int* __restrict__ degdis) {
    int i = blockIdx.x * 256 + threadIdx.x;
    if (i < NN) {
        int d = degdis[i];
        ((float*)degdis)[i] = 1.0f / sqrtf((float)(d + 1));  // +1 self loop
    }
}

// bucketed scatter: pass p writes only cols in [p*NB8, (p+1)*NB8)
__global__ __launch_bounds__(256) void k_scatter(const int* __restrict__ ei, const int* __restrict__ colptr,
                                                 int* __restrict__ cursor, int* __restrict__ csr_row, int p) {
    int e = blockIdx.x * 256 + threadIdx.x;
    if (e < NE) {
        int c = ei[NE + e];
        int lo = p * NB8;
        if (c >= lo && c < lo + NB8) {
            int r = ei[e];
            int pos = colptr[c] + atomicAdd(&cursor[c], 1);
            csr_row[pos] = r;
        }
    }
}

// ---------------- x0 stage: h0 = fp16(dis .* x0); out = b32 + x0@W32_0^T; ring0 = fp16(mynorm(x0))
__global__ __launch_bounds__(256) void k_x0(const float* __restrict__ x, const float* __restrict__ W1,
                                            const float* __restrict__ b1, const float* __restrict__ W32,
                                            const float* __restrict__ b32, const float* __restrict__ dis,
                                            __half* __restrict__ h0, __half* __restrict__ ring0,
                                            float* __restrict__ out, float* __restrict__ Mhat,
                                            float* __restrict__ SCar) {
    __shared__ float sW1[32 * 128];
    __shared__ float sW32[64 * 32];
    __shared__ float sb1[32], sb32[64];
    int t = threadIdx.x;
    if (blockIdx.x == 0 && t == 0) SCar[0] = 1.0f;  // scale of h0 storage
    for (int i = t; i < 4096; i += 256) sW1[i] = W1[i];
    for (int i = t; i < 2048; i += 256) sW32[i] = W32[(i >> 5) * 1024 + (i & 31)];
    if (t < 32) sb1[t] = b1[t];
    if (t < 64) sb32[t] = b32[t];
    __syncthreads();
    int node = blockIdx.x * 256 + t;
    if (node >= NN) return;

    float acc[32];
#pragma unroll
    for (int c = 0; c < 32; c++) acc[c] = sb1[c];
    const float4* xr4 = (const float4*)(x + (long)node * 128);
    for (int q = 0; q < 32; q++) {
        float4 xv = xr4[q];
#pragma unroll
        for (int c = 0; c < 32; c++) {
            acc[c] += xv.x * sW1[c * 128 + q * 4] + xv.y * sW1[c * 128 + q * 4 + 1] +
                      xv.z * sW1[c * 128 + q * 4 + 2] + xv.w * sW1[c * 128 + q * 4 + 3];
        }
    }
    // relu + mynorm
    float mn = 1e30f, mx = -1e30f;
#pragma unroll
    for (int c = 0; c < 32; c++) {
        acc[c] = fmaxf(acc[c], 0.f);
        mn = fminf(mn, acc[c]);
        mx = fmaxf(mx, acc[c]);
    }
    float inv = 2.f / (mx - mn + 1e-8f);
#pragma unroll
    for (int c = 0; c < 32; c++) acc[c] = inv * (acc[c] - mn) - 1.f;  // x0 (unscaled), range [-1,1]
    // store h0 = fp16(dis * x0)
    float sc = dis[node];
    __half2* hr = (__half2*)(h0 + (long)node * 32);
#pragma unroll
    for (int q = 0; q < 16; q++) hr[q] = __floats2half2_rn(sc * acc[2 * q], sc * acc[2 * q + 1]);
    if (t == 0 && (blockIdx.x & 15) == 0) atomicMax((int*)&Mhat[0], __float_as_int(sc));
    // m0 = mynorm(x0)
    float mn2 = 1e30f, mx2 = -1e30f;
#pragma unroll
    for (int c = 0; c < 32; c++) {
        mn2 = fminf(mn2, acc[c]);
        mx2 = fmaxf(mx2, acc[c]);
    }
    float inv2 = 2.f / (mx2 - mn2 + 1e-8f);
    __half2* rr = (__half2*)(ring0 + (long)node * 32);
#pragma unroll
    for (int q = 0; q < 16; q++)
        rr[q] = __floats2half2_rn(inv2 * (acc[2 * q] - mn2) - 1.f, inv2 * (acc[2 * q + 1] - mn2) - 1.f);
    float* orow = out + (long)node * 64;
    for (int o = 0; o < 64; o++) {
        float a = sb32[o];
#pragma unroll
        for (int j = 0; j < 32; j++) a += sW32[o * 32 + j] * acc[j];
        orow[o] = a;
    }
}

// ---------------- one SGConv layer; 8 nodes/wave, 8 lanes/node, 8B gathers (R8 body) ----------------
__global__ __launch_bounds__(256, 3) void k_layer(const __half* __restrict__ hin, __half* __restrict__ hout,
                                                  __half* __restrict__ ring, const float* __restrict__ dis,
                                                  const int* __restrict__ colptr, const int* __restrict__ csr_row,
                                                  const float* __restrict__ Wck, const float* __restrict__ bck,
                                                  const float* __restrict__ W32k, float* __restrict__ out,
                                                  float* __restrict__ Mhat, float* __restrict__ SCar, int k,
                                                  int rawfeat) {
    __shared__ float sWc[32 * 33];
    __shared__ float sW[64 * 33];
    __shared__ float sbc[32];
    int t = threadIdx.x;
    float SCin = SCar[k - 1];
    float SCk = SCin * fmaxf(Mhat[k - 1], 1e-30f);
    if (t == 0) SCar[k] = SCk;  // all blocks write same value
    float invSCk = 1.0f / SCk;
    for (int i = t; i < 1024; i += 256) sWc[(i >> 5) * 33 + (i & 31)] = Wck[i];
    for (int i = t; i < 2048; i += 256) sW[(i >> 5) * 33 + (i & 31)] = W32k[(i >> 5) * 1024 + (i & 31)];
    if (t < 32) sbc[t] = bck[t];
    __syncthreads();

    int wave = t >> 6, lane = t & 63;
    int sub = lane >> 3, q = lane & 7;
    int node = blockIdx.x * 32 + wave * 8 + sub;  // 3125*32 == 100000 exactly
    int sl = sub * 8;                              // lane base of my 8-group

    const uint2* __restrict__ h2 = (const uint2*)hin;  // row stride = 8 uint2 (32 halves); 64B-aligned rows
    int e0 = colptr[node], e1 = colptr[node + 1];
    float di = dis[node];

    float a0, a1, a2, a3, b0 = 0.f, b1 = 0.f, b2 = 0.f, b3 = 0.f;
    {   // self-loop row
        uint2 u = h2[(long)node * 8 + q];
        float2 lo = __half22float2(*(__half2*)&u.x);
        float2 hi = __half22float2(*(__half2*)&u.y);
        a0 = lo.x; a1 = lo.y; a2 = hi.x; a3 = hi.y;
    }
    int base = e0;
    while (base + 8 <= e1) {
        int r = csr_row[base + q];  // 8 lanes fetch 8 edges of my node
#pragma unroll
        for (int j = 0; j < 8; j += 2) {
            int r0 = __shfl(r, sl + j, 64);
            int r1 = __shfl(r, sl + j + 1, 64);
            uint2 u0 = h2[(long)r0 * 8 + q];
            uint2 u1 = h2[(long)r1 * 8 + q];
            float2 lo0 = __half22float2(*(__half2*)&u0.x), hi0 = __half22float2(*(__half2*)&u0.y);
            float2 lo1 = __half22float2(*(__half2*)&u1.x), hi1 = __half22float2(*(__half2*)&u1.y);
            a0 += lo0.x; a1 += lo0.y; a2 += hi0.x; a3 += hi0.y;
            b0 += lo1.x; b1 += lo1.y; b2 += hi1.x; b3 += hi1.y;
        }
        base += 8;
    }
    int rem = e1 - base;
    if (rem > 0) {
        int r = (q < rem) ? csr_row[base + q] : 0;
        for (int j = 0; j < rem; j++) {
            int rj = __shfl(r, sl + j, 64);
            uint2 u = h2[(long)rj * 8 + q];
            float2 lo = __half22float2(*(__half2*)&u.x), hi = __half22float2(*(__half2*)&u.y);
            a0 += lo.x; a1 += lo.y; a2 += hi.x; a3 += hi.y;
        }
    }
    float g0 = di * (a0 + b0), g1 = di * (a1 + b1), g2 = di * (a2 + b2), g3 = di * (a3 + b3);
    // g* = ghat = (A h)[node][4q..4q+3] / SCin

    // y = SCin*(ghat @ Wc^T) + bc for my 4 channels
    const float* wr0 = &sWc[(4 * q + 0) * 33];
    const float* wr1 = &sWc[(4 * q + 1) * 33];
    const float* wr2 = &sWc[(4 * q + 2) * 33];
    const float* wr3 = &sWc[(4 * q + 3) * 33];
    float y0 = 0.f, y1 = 0.f, y2 = 0.f, y3 = 0.f;
#pragma unroll
    for (int s = 0; s < 8; s++) {
        float t0 = __shfl(g0, sl + s, 64);
        float t1 = __shfl(g1, sl + s, 64);
        float t2 = __shfl(g2, sl + s, 64);
        float t3 = __shfl(g3, sl + s, 64);
        int jb = 4 * s;
        y0 += wr0[jb] * t0 + wr0[jb + 1] * t1 + wr0[jb + 2] * t2 + wr0[jb + 3] * t3;
        y1 += wr1[jb] * t0 + wr1[jb + 1] * t1 + wr1[jb + 2] * t2 + wr1[jb + 3] * t3;
        y2 += wr2[jb] * t0 + wr2[jb + 1] * t1 + wr2[jb + 2] * t2 + wr2[jb + 3] * t3;
        y3 += wr3[jb] * t0 + wr3[jb + 1] * t1 + wr3[jb + 2] * t2 + wr3[jb + 3] * t3;
    }
    y0 = SCin * y0 + sbc[4 * q + 0];
    y1 = SCin * y1 + sbc[4 * q + 1];
    y2 = SCin * y2 + sbc[4 * q + 2];
    y3 = SCin * y3 + sbc[4 * q + 3];

    // store hout = fp16(di * y / SCk)
    {
        __half2 p0 = __floats2half2_rn(di * y0 * invSCk, di * y1 * invSCk);
        __half2 p1 = __floats2half2_rn(di * y2 * invSCk, di * y3 * invSCk);
        uint2 pw;
        pw.x = *(unsigned int*)&p0;
        pw.y = *(unsigned int*)&p1;
        ((uint2*)hout)[(long)node * 8 + q] = pw;
    }

    // mynorm over 32 channels = reduce over 4 regs x 8 lanes
    float mn = fminf(fminf(y0, y1), fminf(y2, y3));
    float mx = fmaxf(fmaxf(y0, y1), fmaxf(y2, y3));
#pragma unroll
    for (int m = 1; m < 8; m <<= 1) {
        mn = fminf(mn, __shfl_xor(mn, m, 64));
        mx = fmaxf(mx, __shfl_xor(mx, m, 64));
    }
    float inv = 2.f / (mx - mn + 1e-8f);
    float mv0 = inv * (y0 - mn) - 1.f, mv1 = inv * (y1 - mn) - 1.f;
    float mv2 = inv * (y2 - mn) - 1.f, mv3 = inv * (y3 - mn) - 1.f;

    // sample stored-magnitude max for next layer's scale
    if ((blockIdx.x & 15) == 0 && q == 0) {
        float rowmax = fmaxf(fabsf(mn), fabsf(mx));
        atomicMax((int*)&Mhat[k], __float_as_int(di * rowmax * invSCk));
    }

    float f0, f1, f2, f3;
    if (rawfeat) {
        f0 = y0; f1 = y1; f2 = y2; f3 = y3;
    } else {
        uint2 rv = ((const uint2*)ring)[(long)node * 8 + q];
        float2 rlo = __half22float2(*(__half2*)&rv.x);
        float2 rhi = __half22float2(*(__half2*)&rv.y);
        f0 = mv0 - rlo.x; f1 = mv1 - rlo.y; f2 = mv2 - rhi.x; f3 = mv3 - rhi.y;
    }
    {
        __half2 p0 = __floats2half2_rn(mv0, mv1);
        __half2 p1 = __floats2half2_rn(mv2, mv3);
        uint2 pw;
        pw.x = *(unsigned int*)&p0;
        pw.y = *(unsigned int*)&p1;
        ((uint2*)ring)[(long)node * 8 + q] = pw;
    }

    // out[node][8q..8q+7] += f @ W32_k^T rows
    float o0 = 0.f, o1 = 0.f, o2 = 0.f, o3 = 0.f, o4 = 0.f, o5 = 0.f, o6 = 0.f, o7 = 0.f;
#pragma unroll
    for (int s = 0; s < 8; s++) {
        float t0 = __shfl(f0, sl + s, 64);
        float t1 = __shfl(f1, sl + s, 64);
        float t2 = __shfl(f2, sl + s, 64);
        float t3 = __shfl(f3, sl + s, 64);
        int jb = 4 * s;
        const float* w = &sW[(8 * q) * 33 + jb];
        o0 += w[0] * t0 + w[1] * t1 + w[2] * t2 + w[3] * t3; w += 33;
        o1 += w[0] * t0 + w[1] * t1 + w[2] * t2 + w[3] * t3; w += 33;
        o2 += w[0] * t0 + w[1] * t1 + w[2] * t2 + w[3] * t3; w += 33;
        o3 += w[0] * t0 + w[1] * t1 + w[2] * t2 + w[3] * t3; w += 33;
        o4 += w[0] * t0 + w[1] * t1 + w[2] * t2 + w[3] * t3; w += 33;
        o5 += w[0] * t0 + w[1] * t1 + w[2] * t2 + w[3] * t3; w += 33;
        o6 += w[0] * t0 + w[1] * t1 + w[2] * t2 + w[3] * t3; w += 33;
        o7 += w[0] * t0 + w[1] * t1 + w[2] * t2 + w[3] * t3;
    }
    float4* op = (float4*)(out + (long)node * 64 + 8 * q);
    float4 v0 = op[0], v1 = op[1];
    v0.x += o0; v0.y += o1; v0.z += o2; v0.w += o3;
    v1.x += o4; v1.y += o5; v1.z += o6; v1.w += o7;
    op[0] = v0;
    op[1] = v1;
}

extern "C" void kernel_launch(void* const* d_in, const int* in_sizes, int n_in, void* d_out, int out_size,
                              void* d_ws, size_t ws_size, hipStream_t stream) {
    const float* x = (const float*)d_in[0];
    const int* ei = (const int*)d_in[1];
    const float* W1 = (const float*)d_in[2];
    const float* b1 = (const float*)d_in[3];
    const float* Wc = (const float*)d_in[4];
    const float* bc = (const float*)d_in[5];
    const float* W32 = (const float*)d_in[6];
    const float* b32 = (const float*)d_in[7];
    float* out = (float*)d_out;

    // --- workspace layout: cache-line-aligned h buffers FIRST ---
    // align d_ws up to 256B
    uintptr_t base = ((uintptr_t)d_ws + 255) & ~(uintptr_t)255;
    __half* h0 = (__half*)base;                 // NN*32 halves = 6.4MB (64B-aligned rows)
    __half* h1 = h0 + (long)NN * 32;
    __half* ring = h1 + (long)NN * 32;          // 2 slots of NN*32 halves
    int* deg = (int*)(ring + (long)2 * NN * 32);  // NN
    int* cursor = deg + NN;                     // NN
    float* Mhat = (float*)(cursor + NN);        // 64
    float* SCar = Mhat + 64;                    // 64
    int* colptr = (int*)(SCar + 64);            // 100004
    int* bsum = colptr + 100004;                // 1024
    int* csr_row = bsum + 1024;                 // NE
    float* dis = (float*)deg;

    hipMemsetAsync(deg, 0, (2 * NN + 128) * sizeof(int), stream);  // deg + cursor + Mhat + SCar
    k_deg<<<(NE + 255) / 256, 256, 0, stream>>>(ei + NE, deg);
    int NB = (NN + 255) / 256;  // 391
    k_bsum<<<NB, 256, 0, stream>>>(deg, bsum);
    k_scanb<<<1, 512, 0, stream>>>(bsum, NB);
    k_colptr<<<NB, 256, 0, stream>>>(deg, bsum, colptr);
    k_dis<<<(NN + 255) / 256, 256, 0, stream>>>(deg);
    for (int p = 0; p < 8; p++)
        k_scatter<<<(NE + 255) / 256, 256, 0, stream>>>(ei, colptr, cursor, csr_row, p);
    k_x0<<<NB, 256, 0, stream>>>(x, W1, b1, W32, b32, dis, h0, ring, out, Mhat, SCar);

    for (int k = 1; k <= 31; k++) {
        const __half* hin = (k & 1) ? h0 : h1;
        __half* hout = (k & 1) ? h1 : h0;
        __half* ringk = ring + (long)(k & 1) * NN * 32;
        int raw = (k == 1 || k == 16) ? 1 : 0;
        k_layer<<<3125, 256, 0, stream>>>(hin, hout, ringk, dis, colptr, csr_row, Wc + (k - 1) * 1024,
                                          bc + (k - 1) * 32, W32 + 32 * k, out, Mhat, SCar, k, raw);
    }
}